// Round 3
// 705.972 us; speedup vs baseline: 1.1044x; 1.1044x over previous
//
#include <hip/hip_runtime.h>
#include <hip/hip_bf16.h>

// Problem constants (AWQLinear): x[2,2048,4096] f32, q_weight[11008,4096] i32 in [0,16),
// scales[11008,128] f32, input_scale[4096] f32, bias[11008] f32 -> out[2,2048,11008] f32.
#define IN_F   4096
#define OUT_F  11008
#define MROWS  4096      // B*S
#define QBLK   32        // AWQ block
#define BK     64        // GEMM K-tile
#define NKT    (IN_F / BK)   // 64 K-tiles

typedef __attribute__((ext_vector_type(8))) short   bf16x8;  // 8 bf16 in 4 VGPRs
typedef __attribute__((ext_vector_type(8))) unsigned short ushortx8;
typedef __attribute__((ext_vector_type(4))) float   f32x4;

// fp32 -> bf16 round-to-nearest-even
static __device__ __forceinline__ unsigned short f2bf(float f) {
    unsigned int u = __builtin_bit_cast(unsigned int, f);
    u += 0x7fffu + ((u >> 16) & 1u);
    return (unsigned short)(u >> 16);
}

// async global->LDS, 16B per lane. HW dest = wave-uniform base + lane*16.
static __device__ __forceinline__ void gl_lds16(const void* g, void* l) {
    __builtin_amdgcn_global_load_lds((const __attribute__((address_space(1))) void*)g,
                                     (__attribute__((address_space(3))) void*)l,
                                     16, 0, 0);
}

// ---------------- kernel 1: W dequant (int4-as-int32 -> bf16), [OUT_F][IN_F] ----------------
__global__ __launch_bounds__(256) void dequant_w_kernel(const int* __restrict__ q,
                                                        const float* __restrict__ scales,
                                                        unsigned short* __restrict__ W) {
    const size_t base = ((size_t)blockIdx.x * 256 + threadIdx.x) * 8;   // 8 elems/thread
    const int4 q0 = *(const int4*)(q + base);
    const int4 q1 = *(const int4*)(q + base + 4);
    const int n = (int)(base >> 12);          // /IN_F
    const int k = (int)(base & (IN_F - 1));
    const float s = scales[(n << 7) | (k >> 5)];   // 8 consecutive k share one 32-block
    ushortx8 v;
    v[0] = f2bf(((float)q0.x - 8.0f) * s);
    v[1] = f2bf(((float)q0.y - 8.0f) * s);
    v[2] = f2bf(((float)q0.z - 8.0f) * s);
    v[3] = f2bf(((float)q0.w - 8.0f) * s);
    v[4] = f2bf(((float)q1.x - 8.0f) * s);
    v[5] = f2bf(((float)q1.y - 8.0f) * s);
    v[6] = f2bf(((float)q1.z - 8.0f) * s);
    v[7] = f2bf(((float)q1.w - 8.0f) * s);
    *(ushortx8*)(W + base) = v;
}

// ---------------- kernel 2: x / input_scale -> bf16, [MROWS][IN_F] ----------------
__global__ __launch_bounds__(256) void scale_x_kernel(const float* __restrict__ x,
                                                      const float* __restrict__ alpha,
                                                      unsigned short* __restrict__ Xs) {
    const size_t base = ((size_t)blockIdx.x * 256 + threadIdx.x) * 8;
    const int k = (int)(base & (IN_F - 1));
    const float4 x0 = *(const float4*)(x + base);
    const float4 x1 = *(const float4*)(x + base + 4);
    const float4 a0 = *(const float4*)(alpha + k);
    const float4 a1 = *(const float4*)(alpha + k + 4);
    ushortx8 v;
    v[0] = f2bf(x0.x / a0.x);
    v[1] = f2bf(x0.y / a0.y);
    v[2] = f2bf(x0.z / a0.z);
    v[3] = f2bf(x0.w / a0.w);
    v[4] = f2bf(x1.x / a1.x);
    v[5] = f2bf(x1.y / a1.y);
    v[6] = f2bf(x1.z / a1.z);
    v[7] = f2bf(x1.w / a1.w);
    *(ushortx8*)(Xs + base) = v;
}

// ---------------- kernel 3: 256x256 8-phase GEMM, C = A * W^T + bias ----------------
// Wave->output mapping is INTERLEAVED so each phase's ds_reads touch exactly one half-tile
// for ALL waves (fix of the R2 race):
//   A row = mt*32 + wm*16 + fr  -> mt 0-3 entirely in A0 (rows 0-127), mt 4-7 in A1.
//   B col = nt*64 + wn*16 + fr  -> nt 0-1 entirely in B0 (cols 0-127), nt 2-3 in B1.
// Phases per K-tile t (each: {ds_read subtile | issue 1 half-tile DMA} -> barrier ->
// setprio(1) 16xMFMA setprio(0) -> counted vmcnt -> barrier):
//   P0: read A0(mt0-3)+B0(nt0-1); stage B0(t+1)->nxt; mfma Q0; vmcnt(6)  [forces B1(t)]
//   P1: read B1(nt2-3);           stage B1(t+1)->nxt; mfma Q1; vmcnt(6)  [forces A1(t)]
//   P2: read A1(mt4-7);           stage A1(t+1)->nxt; mfma Q2; (no vmcnt)
//   P3: (regs only)               stage A0(t+2)->cur; mfma Q3; vmcnt(6)  [forces A0,B0(t+1)]
// Stages are issued UNCONDITIONALLY with clamped K-tile index so the vmcnt op-ledger is
// uniform for every t (tail dummies rewrite never-again-read regions; ~0.5% extra traffic).
// Ledger (2 VMEM ops/stage): prologue 10 ops, vmcnt(6) retires A0(0)/B0(0); steady state
// P0/P1: 8 outstanding -> retire 2; P3: 10 outstanding -> retire 4 = A0,B0(t+1).
// WAR: every DMA dest's last ds_read is >=3 barriers earlier, and those reads complete
// before that phase's MFMA (compiler lgkmcnt), hence before the reading wave passes the
// phase-end barrier.
// R4 hardening: drain vmcnt(0) after the K-loop — s_endpgm does NOT wait for in-flight
// global_load_lds, and a stale DMA landing after LDS is reassigned to a newly dispatched
// block would corrupt it (the tail dummies guarantee up to 10 ops in flight at loop exit).
//
// LDS swizzle (T2): LDS(row, slot16B) holds global(row, slot ^ (row&7)); global_load_lds
// writes linearly so the SOURCE address carries the XOR; fragment ds_read_b128 applies the
// same XOR -> 8 consecutive lanes hit 8 distinct 16B slots = all 32 banks, conflict-free.
__global__ __launch_bounds__(512, 2) void gemm_bt_kernel(const unsigned short* __restrict__ A,
                                                         const unsigned short* __restrict__ Bw,
                                                         const float* __restrict__ bias,
                                                         float* __restrict__ C) {
    __shared__ __align__(16) unsigned short As[2 * 256 * BK];   // 64 KiB
    __shared__ __align__(16) unsigned short Bs[2 * 256 * BK];   // 64 KiB

    const int tid  = threadIdx.x;
    const int wave = tid >> 6;
    const int lane = tid & 63;

    // T1: XCD-aware bijective swizzle. 688 blocks = 8 XCDs * 86. m-major inside a chunk:
    // 16 consecutive blocks share one 256x4096 B-panel (2 MB) in their XCD's L2.
    const int bid   = blockIdx.x;
    const int wgid  = (bid & 7) * 86 + (bid >> 3);
    const int mtile = wgid & 15;
    const int ntile = wgid >> 4;
    const int m0 = mtile << 8;
    const int n0 = ntile << 8;

    const int wm = wave >> 2;    // 0..1 : 16-row stripe within each 32-row A group
    const int wn = wave & 3;     // 0..3 : 16-col stripe within each 64-col B group

    // ---- staging addresses (per half-tile: 2 x 16B per thread) ----
    // chunk = j*8 + wave (j=0,1); row = chunk*8 + lane>>3; dst slot = lane&7.
    // source slot = dstslot ^ (row&7) = (lane&7) ^ (lane>>3)  (row&7 == lane>>3).
    const int l3   = lane >> 3;
    const int l7   = lane & 7;
    const int swzE = (l7 ^ l3) << 3;                     // swizzled k offset, elems
    const unsigned short* gA = A  + (size_t)(m0 + wave * 8 + l3) * IN_F + swzE;
    const unsigned short* gB = Bw + (size_t)(n0 + wave * 8 + l3) * IN_F + swzE;
    const int ldst = wave * 512 + lane * 8;              // j=0 chunk dest, elems

#define STAGE_A(buf, kt, half) do {                                              \
        const unsigned short* _g = gA + (size_t)(half) * 128 * IN_F + (size_t)(kt) * BK; \
        unsigned short* _l = As + (buf) * 16384 + (half) * 8192 + ldst;          \
        gl_lds16(_g, _l);                                                        \
        gl_lds16(_g + (size_t)64 * IN_F, _l + 4096); } while (0)
#define STAGE_B(buf, kt, half) do {                                              \
        const unsigned short* _g = gB + (size_t)(half) * 128 * IN_F + (size_t)(kt) * BK; \
        unsigned short* _l = Bs + (buf) * 16384 + (half) * 8192 + ldst;          \
        gl_lds16(_g, _l);                                                        \
        gl_lds16(_g + (size_t)64 * IN_F, _l + 4096); } while (0)

    // ---- ds-read fragment offsets (16x16x32: row = lane&15, k = (lane>>4)*8 + j) ----
    // LDS elem offset for tile row r = r*64 (halves are contiguous: half*8192 = 128*64).
    // row&7 == fr&7 == l7 for every fragment (mt*32, wm*16, nt*64, wn*16 all = 0 mod 8).
    const int kg   = lane >> 4;                  // 0..3
    const int fr   = lane & 15;
    const int rowA = (wm * 16 + fr) * BK;        // + mt*2048 per 32-row step
    const int rowB = (wn * 16 + fr) * BK;        // + nt*4096 per 64-col step
    const int sK0  = ((kg)     ^ l7) << 3;       // kh=0 swizzled slot (k 0..31)
    const int sK1  = ((kg + 4) ^ l7) << 3;       // kh=1 swizzled slot (k 32..63)

    f32x4  acc[8][4] = {};
    bf16x8 af[4][2], bA[2][2], bB[2][2];

    // ---- prologue: tile0 fully + A0 of tile1 (10 VMEM ops outstanding) ----
    STAGE_A(0, 0, 0);
    STAGE_B(0, 0, 0);
    STAGE_B(0, 0, 1);
    STAGE_A(0, 0, 1);
    STAGE_A(1, 1, 0);
    asm volatile("s_waitcnt vmcnt(6)" ::: "memory");   // A0(0), B0(0) landed
    __builtin_amdgcn_s_barrier();

#pragma unroll 2
    for (int t = 0; t < NKT; ++t) {
        const int cur = t & 1;
        const int nxt = cur ^ 1;
        const unsigned short* cA = As + cur * 16384;
        const unsigned short* cB = Bs + cur * 16384;
        const int ktn  = (t + 1 < NKT) ? t + 1 : NKT - 1;   // clamped: uniform issue count
        const int ktn2 = (t + 2 < NKT) ? t + 2 : NKT - 1;

        // ================ P0 : Q0 = mt0-3 x nt0-1 (reads A0, B0) ================
#pragma unroll
        for (int mt = 0; mt < 4; ++mt) {
            af[mt][0] = *(const bf16x8*)(cA + rowA + mt * 2048 + sK0);
            af[mt][1] = *(const bf16x8*)(cA + rowA + mt * 2048 + sK1);
        }
#pragma unroll
        for (int nt = 0; nt < 2; ++nt) {
            bA[nt][0] = *(const bf16x8*)(cB + rowB + nt * 4096 + sK0);
            bA[nt][1] = *(const bf16x8*)(cB + rowB + nt * 4096 + sK1);
        }
        STAGE_B(nxt, ktn, 0);
        __builtin_amdgcn_s_barrier();
        __builtin_amdgcn_s_setprio(1);
#pragma unroll
        for (int mt = 0; mt < 4; ++mt)
#pragma unroll
            for (int nt = 0; nt < 2; ++nt) {
                acc[mt][nt] = __builtin_amdgcn_mfma_f32_16x16x32_bf16(af[mt][0], bA[nt][0], acc[mt][nt], 0, 0, 0);
                acc[mt][nt] = __builtin_amdgcn_mfma_f32_16x16x32_bf16(af[mt][1], bA[nt][1], acc[mt][nt], 0, 0, 0);
            }
        __builtin_amdgcn_s_setprio(0);
        asm volatile("s_waitcnt vmcnt(6)" ::: "memory");   // forces B1(t) landed
        __builtin_amdgcn_s_barrier();

        // ================ P1 : Q1 = mt0-3 x nt2-3 (reads B1) ================
#pragma unroll
        for (int nt = 0; nt < 2; ++nt) {
            bB[nt][0] = *(const bf16x8*)(cB + rowB + (nt + 2) * 4096 + sK0);
            bB[nt][1] = *(const bf16x8*)(cB + rowB + (nt + 2) * 4096 + sK1);
        }
        STAGE_B(nxt, ktn, 1);
        __builtin_amdgcn_s_barrier();
        __builtin_amdgcn_s_setprio(1);
#pragma unroll
        for (int mt = 0; mt < 4; ++mt)
#pragma unroll
            for (int nt = 0; nt < 2; ++nt) {
                acc[mt][nt + 2] = __builtin_amdgcn_mfma_f32_16x16x32_bf16(af[mt][0], bB[nt][0], acc[mt][nt + 2], 0, 0, 0);
                acc[mt][nt + 2] = __builtin_amdgcn_mfma_f32_16x16x32_bf16(af[mt][1], bB[nt][1], acc[mt][nt + 2], 0, 0, 0);
            }
        __builtin_amdgcn_s_setprio(0);
        asm volatile("s_waitcnt vmcnt(6)" ::: "memory");   // forces A1(t) landed
        __builtin_amdgcn_s_barrier();

        // ================ P2 : Q2 = mt4-7 x nt2-3 (reads A1) ================
#pragma unroll
        for (int mt = 0; mt < 4; ++mt) {
            af[mt][0] = *(const bf16x8*)(cA + rowA + (mt + 4) * 2048 + sK0);
            af[mt][1] = *(const bf16x8*)(cA + rowA + (mt + 4) * 2048 + sK1);
        }
        STAGE_A(nxt, ktn, 1);
        __builtin_amdgcn_s_barrier();
        __builtin_amdgcn_s_setprio(1);
#pragma unroll
        for (int mt = 0; mt < 4; ++mt)
#pragma unroll
            for (int nt = 0; nt < 2; ++nt) {
                acc[mt + 4][nt + 2] = __builtin_amdgcn_mfma_f32_16x16x32_bf16(af[mt][0], bB[nt][0], acc[mt + 4][nt + 2], 0, 0, 0);
                acc[mt + 4][nt + 2] = __builtin_amdgcn_mfma_f32_16x16x32_bf16(af[mt][1], bB[nt][1], acc[mt + 4][nt + 2], 0, 0, 0);
            }
        __builtin_amdgcn_s_setprio(0);
        __builtin_amdgcn_s_barrier();                      // no vmcnt here

        // ================ P3 : Q3 = mt4-7 x nt0-1 (regs only) ================
        STAGE_A(cur, ktn2, 0);                             // A0(cur): last read was P0
        __builtin_amdgcn_s_barrier();
        __builtin_amdgcn_s_setprio(1);
#pragma unroll
        for (int mt = 0; mt < 4; ++mt)
#pragma unroll
            for (int nt = 0; nt < 2; ++nt) {
                acc[mt + 4][nt] = __builtin_amdgcn_mfma_f32_16x16x32_bf16(af[mt][0], bA[nt][0], acc[mt + 4][nt], 0, 0, 0);
                acc[mt + 4][nt] = __builtin_amdgcn_mfma_f32_16x16x32_bf16(af[mt][1], bA[nt][1], acc[mt + 4][nt], 0, 0, 0);
            }
        __builtin_amdgcn_s_setprio(0);
        asm volatile("s_waitcnt vmcnt(6)" ::: "memory");   // forces A0(t+1), B0(t+1) landed
        __builtin_amdgcn_s_barrier();
    }
#undef STAGE_A
#undef STAGE_B

    // Drain in-flight LDS-DMAs before the wave can retire (see header comment).
    asm volatile("s_waitcnt vmcnt(0)" ::: "memory");

    // ---- epilogue: C/D layout col = lane&15, row = (lane>>4)*4 + reg. + bias ----
    const int cr = (lane >> 4) << 2;
    const int cc = lane & 15;
#pragma unroll
    for (int nt = 0; nt < 4; ++nt) {
        const int gn = n0 + nt * 64 + wn * 16 + cc;
        const float bv = bias[gn];
#pragma unroll
        for (int mt = 0; mt < 8; ++mt) {
            const int gm = m0 + mt * 32 + wm * 16 + cr;
            float* cp = C + (size_t)gm * OUT_F + gn;
#pragma unroll
            for (int r = 0; r < 4; ++r)
                cp[(size_t)r * OUT_F] = acc[mt][nt][r] + bv;
        }
    }
}

extern "C" void kernel_launch(void* const* d_in, const int* in_sizes, int n_in,
                              void* d_out, int out_size, void* d_ws, size_t ws_size,
                              hipStream_t stream) {
    const float* x      = (const float*)d_in[0];
    const int*   qw     = (const int*)  d_in[1];
    const float* scales = (const float*)d_in[2];
    const float* alpha  = (const float*)d_in[3];
    const float* bias   = (const float*)d_in[4];
    float* out = (float*)d_out;

    // Workspace: W bf16 [OUT_F][IN_F] (~86 MiB) then Xs bf16 [MROWS][IN_F] (32 MiB).
    unsigned short* W  = (unsigned short*)d_ws;
    unsigned short* Xs = (unsigned short*)((char*)d_ws + (size_t)OUT_F * IN_F * 2);

    dequant_w_kernel<<<(OUT_F * IN_F) / (8 * 256), 256, 0, stream>>>(qw, scales, W);
    scale_x_kernel <<<(MROWS * IN_F) / (8 * 256), 256, 0, stream>>>(x, alpha, Xs);
    gemm_bt_kernel<<<(MROWS / 256) * (OUT_F / 256), 512, 0, stream>>>(Xs, W, bias, out);
}

// Round 4
// 686.716 us; speedup vs baseline: 1.1354x; 1.0280x over previous
//
#include <hip/hip_runtime.h>
#include <hip/hip_bf16.h>

// Problem constants (AWQLinear): x[2,2048,4096] f32, q_weight[11008,4096] i32 in [0,16),
// scales[11008,128] f32, input_scale[4096] f32, bias[11008] f32 -> out[2,2048,11008] f32.
#define IN_F   4096
#define OUT_F  11008
#define MROWS  4096      // B*S
#define QBLK   32        // AWQ block
#define BK     64        // GEMM K-tile
#define NKT    (IN_F / BK)   // 64 K-tiles

typedef __attribute__((ext_vector_type(8))) short   bf16x8;  // 8 bf16 in 4 VGPRs
typedef __attribute__((ext_vector_type(8))) unsigned short ushortx8;
typedef __attribute__((ext_vector_type(4))) float   f32x4;

// fp32 -> bf16 round-to-nearest-even
static __device__ __forceinline__ unsigned short f2bf(float f) {
    unsigned int u = __builtin_bit_cast(unsigned int, f);
    u += 0x7fffu + ((u >> 16) & 1u);
    return (unsigned short)(u >> 16);
}

// async global->LDS, 16B per lane. HW dest = wave-uniform base + lane*16.
static __device__ __forceinline__ void gl_lds16(const void* g, void* l) {
    __builtin_amdgcn_global_load_lds((const __attribute__((address_space(1))) void*)g,
                                     (__attribute__((address_space(3))) void*)l,
                                     16, 0, 0);
}

// ---------------- kernel 1: W dequant (int4-as-int32 -> bf16), [OUT_F][IN_F] ----------------
__global__ __launch_bounds__(256) void dequant_w_kernel(const int* __restrict__ q,
                                                        const float* __restrict__ scales,
                                                        unsigned short* __restrict__ W) {
    const size_t base = ((size_t)blockIdx.x * 256 + threadIdx.x) * 8;   // 8 elems/thread
    const int4 q0 = *(const int4*)(q + base);
    const int4 q1 = *(const int4*)(q + base + 4);
    const int n = (int)(base >> 12);          // /IN_F
    const int k = (int)(base & (IN_F - 1));
    const float s = scales[(n << 7) | (k >> 5)];   // 8 consecutive k share one 32-block
    ushortx8 v;
    v[0] = f2bf(((float)q0.x - 8.0f) * s);
    v[1] = f2bf(((float)q0.y - 8.0f) * s);
    v[2] = f2bf(((float)q0.z - 8.0f) * s);
    v[3] = f2bf(((float)q0.w - 8.0f) * s);
    v[4] = f2bf(((float)q1.x - 8.0f) * s);
    v[5] = f2bf(((float)q1.y - 8.0f) * s);
    v[6] = f2bf(((float)q1.z - 8.0f) * s);
    v[7] = f2bf(((float)q1.w - 8.0f) * s);
    *(ushortx8*)(W + base) = v;
}

// ---------------- kernel 2: x / input_scale -> bf16, [MROWS][IN_F] ----------------
__global__ __launch_bounds__(256) void scale_x_kernel(const float* __restrict__ x,
                                                      const float* __restrict__ alpha,
                                                      unsigned short* __restrict__ Xs) {
    const size_t base = ((size_t)blockIdx.x * 256 + threadIdx.x) * 8;
    const int k = (int)(base & (IN_F - 1));
    const float4 x0 = *(const float4*)(x + base);
    const float4 x1 = *(const float4*)(x + base + 4);
    const float4 a0 = *(const float4*)(alpha + k);
    const float4 a1 = *(const float4*)(alpha + k + 4);
    ushortx8 v;
    v[0] = f2bf(x0.x / a0.x);
    v[1] = f2bf(x0.y / a0.y);
    v[2] = f2bf(x0.z / a0.z);
    v[3] = f2bf(x0.w / a0.w);
    v[4] = f2bf(x1.x / a1.x);
    v[5] = f2bf(x1.y / a1.y);
    v[6] = f2bf(x1.z / a1.z);
    v[7] = f2bf(x1.w / a1.w);
    *(ushortx8*)(Xs + base) = v;
}

// ---------------- kernel 3: 256x256 GEMM, minimal-sync 4-phase pipeline ----------------
// R5: R4's counters showed MfmaUtil 39% / stalls ~48% -- the 8-barrier+3-vmcnt/K-tile
// lockstep (1 block/CU) serialized every ds_read batch and barrier skew.  This version
// keeps R4's data layout + ledger but syncs only TWICE per K-tile.
//
// Interleaved mapping (each phase reads exactly one half-tile for ALL waves):
//   A row = mt*32 + wm*16 + fr  -> mt 0-3 in A0 (rows 0-127), mt 4-7 in A1.
//   B col = nt*64 + wn*16 + fr  -> nt 0-1 in B0, nt 2-3 in B1.
// Per K-tile t:
//   P0: stage B0(t+1)->nxt; read af(mt0-3)x8 + bA(nt0-1)x4; MFMA Q0; vmcnt(4); BARRIER
//       [vmcnt(4) forces BOTH B1(t) and A1(t) -- the oldest 4 ops -- so P1's and P2's
//        reads are covered by this single sync point]
//   P1: stage B1(t+1)->nxt; read bB(nt2-3)x4;  MFMA Q1          (free-run, no sync)
//   P2: stage A1(t+1)->nxt; read af(mt4-7)x8;  MFMA Q2          (free-run, no sync)
//   P3: stage A0(t+2)->cur;                    MFMA Q3; vmcnt(6); BARRIER
//       [vmcnt(6) forces A0(t+1), B0(t+1) for the next P0's reads]
// Free-run P1->P3: cross-wave skew overlaps one wave's ds_reads with another's MFMA
// (the m114 implicit-overlap mechanism) -- previously killed by per-phase barriers.
// Hazard audit: collective-stage->read needs {every wave vmcnt-forces its ops}+barrier:
//   af/bA(t) forced at t-1.P3-end; bB/af2(t) forced at t.P0-end.  WAR: each DMA dest's
//   last reads complete (compiler lgkmcnt before consuming MFMA) before a barrier that
//   all staging waves have passed: A0-cur (restaged P3) last read P0 < P0-end barrier;
//   B1/A1/B0-nxt last read one tile ago.  Ledger uniform via clamped tail dummies:
//   tile-start in-flight = {B1(t),A1(t),A0(t+1)} = 6 ops; P0-end 8 -> vmcnt(4);
//   P3-end 10 -> vmcnt(6).  Post-loop vmcnt(0): s_endpgm does not drain LDS-DMA.
//
// LDS swizzle (T2): LDS(row, slot16B) holds global(row, slot ^ (row&7)); source address
// carries the XOR (global_load_lds writes linearly); fragment ds_read_b128 applies the
// same XOR -> conflict-free.
__global__ __launch_bounds__(512, 2) void gemm_bt_kernel(const unsigned short* __restrict__ A,
                                                         const unsigned short* __restrict__ Bw,
                                                         const float* __restrict__ bias,
                                                         float* __restrict__ C) {
    __shared__ __align__(16) unsigned short As[2 * 256 * BK];   // 64 KiB
    __shared__ __align__(16) unsigned short Bs[2 * 256 * BK];   // 64 KiB

    const int tid  = threadIdx.x;
    const int wave = tid >> 6;
    const int lane = tid & 63;

    // T1: XCD-aware bijective swizzle. 688 blocks = 8 XCDs * 86. m-major inside a chunk:
    // 16 consecutive blocks share one 256x4096 B-panel (2 MB) in their XCD's L2.
    const int bid   = blockIdx.x;
    const int wgid  = (bid & 7) * 86 + (bid >> 3);
    const int mtile = wgid & 15;
    const int ntile = wgid >> 4;
    const int m0 = mtile << 8;
    const int n0 = ntile << 8;

    const int wm = wave >> 2;    // 0..1 : 16-row stripe within each 32-row A group
    const int wn = wave & 3;     // 0..3 : 16-col stripe within each 64-col B group

    // ---- staging addresses (per half-tile: 2 x 16B per thread) ----
    // chunk = j*8 + wave (j=0,1); row = chunk*8 + lane>>3; dst slot = lane&7.
    // source slot = dstslot ^ (row&7) = (lane&7) ^ (lane>>3).
    const int l3   = lane >> 3;
    const int l7   = lane & 7;
    const int swzE = (l7 ^ l3) << 3;                     // swizzled k offset, elems
    const unsigned short* gA = A  + (size_t)(m0 + wave * 8 + l3) * IN_F + swzE;
    const unsigned short* gB = Bw + (size_t)(n0 + wave * 8 + l3) * IN_F + swzE;
    const int ldst = wave * 512 + lane * 8;              // j=0 chunk dest, elems

#define STAGE_A(buf, kt, half) do {                                              \
        const unsigned short* _g = gA + (size_t)(half) * 128 * IN_F + (size_t)(kt) * BK; \
        unsigned short* _l = As + (buf) * 16384 + (half) * 8192 + ldst;          \
        gl_lds16(_g, _l);                                                        \
        gl_lds16(_g + (size_t)64 * IN_F, _l + 4096); } while (0)
#define STAGE_B(buf, kt, half) do {                                              \
        const unsigned short* _g = gB + (size_t)(half) * 128 * IN_F + (size_t)(kt) * BK; \
        unsigned short* _l = Bs + (buf) * 16384 + (half) * 8192 + ldst;          \
        gl_lds16(_g, _l);                                                        \
        gl_lds16(_g + (size_t)64 * IN_F, _l + 4096); } while (0)

    // ---- ds-read fragment offsets (16x16x32: row = lane&15, k = (lane>>4)*8 + j) ----
    // row&7 == l7 for every fragment (mt*32, wm*16, nt*64, wn*16 all = 0 mod 8... fr&7 = l7).
    const int kg   = lane >> 4;                  // 0..3
    const int fr   = lane & 15;
    const int rowA = (wm * 16 + fr) * BK;        // + mt*2048 per 32-row step
    const int rowB = (wn * 16 + fr) * BK;        // + nt*4096 per 64-col step
    const int sK0  = ((kg)     ^ l7) << 3;       // kh=0 swizzled slot (k 0..31)
    const int sK1  = ((kg + 4) ^ l7) << 3;       // kh=1 swizzled slot (k 32..63)

    f32x4  acc[8][4] = {};
    bf16x8 af[4][2], bA[2][2], bB[2][2];

    // ---- prologue: tile0 fully + A0 of tile1 (10 VMEM ops outstanding) ----
    STAGE_A(0, 0, 0);
    STAGE_B(0, 0, 0);
    STAGE_B(0, 0, 1);
    STAGE_A(0, 0, 1);
    STAGE_A(1, 1, 0);
    asm volatile("s_waitcnt vmcnt(6)" ::: "memory");   // A0(0), B0(0) landed
    __builtin_amdgcn_s_barrier();
    // invariant established: in flight = {B1(0), A1(0), A0(1)} = 6 ops

#pragma unroll 2
    for (int t = 0; t < NKT; ++t) {
        const int cur = t & 1;
        const int nxt = cur ^ 1;
        const unsigned short* cA = As + cur * 16384;
        const unsigned short* cB = Bs + cur * 16384;
        const int ktn  = (t + 1 < NKT) ? t + 1 : NKT - 1;   // clamped: uniform ledger
        const int ktn2 = (t + 2 < NKT) ? t + 2 : NKT - 1;

        // ===== P0 : Q0 = mt0-3 x nt0-1 (reads A0, B0; both forced at t-1.P3) =====
        STAGE_B(nxt, ktn, 0);
#pragma unroll
        for (int mt = 0; mt < 4; ++mt) {
            af[mt][0] = *(const bf16x8*)(cA + rowA + mt * 2048 + sK0);
            af[mt][1] = *(const bf16x8*)(cA + rowA + mt * 2048 + sK1);
        }
#pragma unroll
        for (int nt = 0; nt < 2; ++nt) {
            bA[nt][0] = *(const bf16x8*)(cB + rowB + nt * 4096 + sK0);
            bA[nt][1] = *(const bf16x8*)(cB + rowB + nt * 4096 + sK1);
        }
        __builtin_amdgcn_s_setprio(1);
#pragma unroll
        for (int mt = 0; mt < 4; ++mt)
#pragma unroll
            for (int nt = 0; nt < 2; ++nt) {
                acc[mt][nt] = __builtin_amdgcn_mfma_f32_16x16x32_bf16(af[mt][0], bA[nt][0], acc[mt][nt], 0, 0, 0);
                acc[mt][nt] = __builtin_amdgcn_mfma_f32_16x16x32_bf16(af[mt][1], bA[nt][1], acc[mt][nt], 0, 0, 0);
            }
        __builtin_amdgcn_s_setprio(0);
        asm volatile("s_waitcnt vmcnt(4)" ::: "memory");   // forces B1(t) AND A1(t)
        __builtin_amdgcn_s_barrier();

        // ===== P1 : Q1 = mt0-3 x nt2-3 (reads B1; forced at P0-end) — free-run =====
        STAGE_B(nxt, ktn, 1);
#pragma unroll
        for (int nt = 0; nt < 2; ++nt) {
            bB[nt][0] = *(const bf16x8*)(cB + rowB + (nt + 2) * 4096 + sK0);
            bB[nt][1] = *(const bf16x8*)(cB + rowB + (nt + 2) * 4096 + sK1);
        }
        __builtin_amdgcn_s_setprio(1);
#pragma unroll
        for (int mt = 0; mt < 4; ++mt)
#pragma unroll
            for (int nt = 0; nt < 2; ++nt) {
                acc[mt][nt + 2] = __builtin_amdgcn_mfma_f32_16x16x32_bf16(af[mt][0], bB[nt][0], acc[mt][nt + 2], 0, 0, 0);
                acc[mt][nt + 2] = __builtin_amdgcn_mfma_f32_16x16x32_bf16(af[mt][1], bB[nt][1], acc[mt][nt + 2], 0, 0, 0);
            }
        __builtin_amdgcn_s_setprio(0);

        // ===== P2 : Q2 = mt4-7 x nt2-3 (reads A1; forced at P0-end) — free-run =====
        STAGE_A(nxt, ktn, 1);
#pragma unroll
        for (int mt = 0; mt < 4; ++mt) {
            af[mt][0] = *(const bf16x8*)(cA + rowA + (mt + 4) * 2048 + sK0);
            af[mt][1] = *(const bf16x8*)(cA + rowA + (mt + 4) * 2048 + sK1);
        }
        __builtin_amdgcn_s_setprio(1);
#pragma unroll
        for (int mt = 0; mt < 4; ++mt)
#pragma unroll
            for (int nt = 0; nt < 2; ++nt) {
                acc[mt + 4][nt + 2] = __builtin_amdgcn_mfma_f32_16x16x32_bf16(af[mt][0], bB[nt][0], acc[mt + 4][nt + 2], 0, 0, 0);
                acc[mt + 4][nt + 2] = __builtin_amdgcn_mfma_f32_16x16x32_bf16(af[mt][1], bB[nt][1], acc[mt + 4][nt + 2], 0, 0, 0);
            }
        __builtin_amdgcn_s_setprio(0);

        // ===== P3 : Q3 = mt4-7 x nt0-1 (regs only) =====
        STAGE_A(cur, ktn2, 0);                             // A0(cur): last read at P0
        __builtin_amdgcn_s_setprio(1);
#pragma unroll
        for (int mt = 0; mt < 4; ++mt)
#pragma unroll
            for (int nt = 0; nt < 2; ++nt) {
                acc[mt + 4][nt] = __builtin_amdgcn_mfma_f32_16x16x32_bf16(af[mt][0], bA[nt][0], acc[mt + 4][nt], 0, 0, 0);
                acc[mt + 4][nt] = __builtin_amdgcn_mfma_f32_16x16x32_bf16(af[mt][1], bA[nt][1], acc[mt + 4][nt], 0, 0, 0);
            }
        __builtin_amdgcn_s_setprio(0);
        asm volatile("s_waitcnt vmcnt(6)" ::: "memory");   // forces A0(t+1), B0(t+1)
        __builtin_amdgcn_s_barrier();
    }
#undef STAGE_A
#undef STAGE_B

    // Drain in-flight LDS-DMAs before the wave can retire (s_endpgm does not wait).
    asm volatile("s_waitcnt vmcnt(0)" ::: "memory");

    // ---- epilogue: C/D layout col = lane&15, row = (lane>>4)*4 + reg. + bias ----
    const int cr = (lane >> 4) << 2;
    const int cc = lane & 15;
#pragma unroll
    for (int nt = 0; nt < 4; ++nt) {
        const int gn = n0 + nt * 64 + wn * 16 + cc;
        const float bv = bias[gn];
#pragma unroll
        for (int mt = 0; mt < 8; ++mt) {
            const int gm = m0 + mt * 32 + wm * 16 + cr;
            float* cp = C + (size_t)gm * OUT_F + gn;
#pragma unroll
            for (int r = 0; r < 4; ++r)
                cp[(size_t)r * OUT_F] = acc[mt][nt][r] + bv;
        }
    }
}

extern "C" void kernel_launch(void* const* d_in, const int* in_sizes, int n_in,
                              void* d_out, int out_size, void* d_ws, size_t ws_size,
                              hipStream_t stream) {
    const float* x      = (const float*)d_in[0];
    const int*   qw     = (const int*)  d_in[1];
    const float* scales = (const float*)d_in[2];
    const float* alpha  = (const float*)d_in[3];
    const float* bias   = (const float*)d_in[4];
    float* out = (float*)d_out;

    // Workspace: W bf16 [OUT_F][IN_F] (~86 MiB) then Xs bf16 [MROWS][IN_F] (32 MiB).
    unsigned short* W  = (unsigned short*)d_ws;
    unsigned short* Xs = (unsigned short*)((char*)d_ws + (size_t)OUT_F * IN_F * 2);

    dequant_w_kernel<<<(OUT_F * IN_F) / (8 * 256), 256, 0, stream>>>(qw, scales, W);
    scale_x_kernel <<<(MROWS * IN_F) / (8 * 256), 256, 0, stream>>>(x, alpha, Xs);
    gemm_bt_kernel<<<(MROWS / 256) * (OUT_F / 256), 512, 0, stream>>>(Xs, W, bias, out);
}